// Round 8
// baseline (188.538 us; speedup 1.0000x reference)
//
#include <hip/hip_runtime.h>
#include <hip/hip_bf16.h>
#include <math.h>

#define T_DIM 2048
#define D_DIM 2048
#define H_DIM 16
#define C_DIM 128

typedef __bf16 bf16;
typedef __attribute__((ext_vector_type(8))) __bf16 bf16x8;
typedef __attribute__((ext_vector_type(4))) __bf16 bf16x4;
typedef __attribute__((ext_vector_type(2))) __bf16 bf16x2;
typedef __attribute__((ext_vector_type(4))) float f32x4;

__device__ __forceinline__ void gload_lds16(const void* g, void* l) {
  __builtin_amdgcn_global_load_lds((__attribute__((address_space(1))) void*)g,
                                   (__attribute__((address_space(3))) void*)l,
                                   16, 0, 0);
}

// ---------------- fused fp32 -> bf16 conversion of x, W_attn, W_proj ----------------
__global__ __launch_bounds__(256) void cvt3(
    const float* __restrict__ x, const float* __restrict__ wa, const float* __restrict__ wp,
    bf16* __restrict__ xo, bf16* __restrict__ wao, bf16* __restrict__ wpo)
{
  const int NX = 1048576, NA = 3145728;      // float4 counts: x, W_attn (W_proj = NX)
  int i = blockIdx.x * 256 + threadIdx.x;
  for (; i < 5242880; i += 2048 * 256) {
    const float* s; bf16* d; int off;
    if (i < NX)            { s = x;  d = xo;  off = i; }
    else if (i < NX + NA)  { s = wa; d = wao; off = i - NX; }
    else                   { s = wp; d = wpo; off = i - NX - NA; }
    float4 v = reinterpret_cast<const float4*>(s)[off];
    bf16x4 o;
    o[0] = (bf16)v.x; o[1] = (bf16)v.y; o[2] = (bf16)v.z; o[3] = (bf16)v.w;
    reinterpret_cast<bf16x4*>(d)[off] = o;
  }
}

// ============ 128x384 4-phase GEMM: C = A(MxK) @ B(NxK)^T + bias (fp32 out) ============
// Grid = 256 blocks (100% fill), 8 waves as 2M x 4N (per-wave 64x96). Phases = Gray-order
// output quadrants; fragments held in registers across phases. LDS 128 KB (BK=64 dbuf),
// chunk-XOR swizzle (measured 0 conflicts).
// T4 counted-vmcnt (never drain in steady state). Per K-tile 8 loads/thread issued as
// {A,B0}=4 (P0), {B1}=2 (P1), {B2}=2 (P2). Steady-state outstanding at phase end = 8:
//   end-P3: vmcnt(4) -> A(t+1),B0(t+1) landed for next P0's ds_reads
//   end-P0: vmcnt(6) -> B1(t) landed for P1       end-P1: vmcnt(6) -> B2(t) landed
//   end-P2: none (P3 reuses registers).  Last tile: vmcnt(2)/vmcnt(0)/none.
__global__ __launch_bounds__(512, 2) void gemm384_bt_bias(
    const bf16* __restrict__ A, const bf16* __restrict__ B,
    const float* __restrict__ bias, float* __restrict__ C,
    int M, int N, int K)
{
  __shared__ __align__(16) bf16 Asl[2][128 * 64];  // 32 KB
  __shared__ __align__(16) bf16 Bsl[2][384 * 64];  // 96 KB
  const int tid = threadIdx.x;
  const int lane = tid & 63;
  const int wv = tid >> 6;          // 0..7
  const int g = lane >> 4, r16 = lane & 15;
  const int wm = wv >> 2;           // 0..1 : 64-row slice
  const int wn = wv & 3;            // 0..3 : 96-col slice

  // XCD swizzle: 256 blocks, 32 contiguous per XCD (2 full A-panel rows each)
  int bid = blockIdx.x;
  int bid2 = (bid & 7) * 32 + (bid >> 3);
  const int ntn = N / 384;
  const int bn = bid2 % ntn, bm = bid2 / ntn;

  const size_t Abase = (size_t)(bm * 128) * K;
  const size_t Bbase = (size_t)(bn * 384) * K;

  f32x4 acc[2][2][2][3] = {};          // [qr][qc][R][F]
  bf16x8 a0[2][2], a1[2][2];           // A row-halves  [R][ks]
  bf16x8 b0[3][2], b1[3][2];           // B col-halves  [F][ks]

  // stage one 128x64 unit (16 KB = 1024 chunks of 16B = 2 loads/thread)
  auto stageA = [&](int bb, int t) {
#pragma unroll
    for (int i = 0; i < 2; ++i) {
      int c = i * 512 + tid;
      int r = c >> 3, p = c & 7, j = p ^ (r & 7);
      gload_lds16(A + Abase + (size_t)r * K + t * 64 + j * 8,
                  (char*)&Asl[bb][0] + (size_t)c * 16);
    }
  };
  auto stageB = [&](int bb, int u, int t) {   // u = 0..2 -> B rows u*128..+127
#pragma unroll
    for (int i = 0; i < 2; ++i) {
      int c = i * 512 + tid;
      int r = c >> 3, p = c & 7, j = p ^ (r & 7);
      gload_lds16(B + Bbase + (size_t)(u * 128 + r) * K + t * 64 + j * 8,
                  (char*)&Bsl[bb][0] + u * 16384 + (size_t)c * 16);
    }
  };
  auto readAh = [&](bf16x8 (&dst)[2][2], int bufi, int qr) {
#pragma unroll
    for (int R = 0; R < 2; ++R) {
      int ar = wm * 64 + qr * 32 + R * 16 + r16;
#pragma unroll
      for (int ks = 0; ks < 2; ++ks)
        dst[R][ks] = *reinterpret_cast<const bf16x8*>(
            &Asl[bufi][ar * 64 + (((ks * 4 + g) ^ (ar & 7)) << 3)]);
    }
  };
  auto readBh = [&](bf16x8 (&dst)[3][2], int bufi, int qc) {
#pragma unroll
    for (int F = 0; F < 3; ++F) {
      int br = wn * 96 + qc * 48 + F * 16 + r16;
#pragma unroll
      for (int ks = 0; ks < 2; ++ks)
        dst[F][ks] = *reinterpret_cast<const bf16x8*>(
            &Bsl[bufi][br * 64 + (((ks * 4 + g) ^ (br & 7)) << 3)]);
    }
  };
  auto mfma12 = [&](f32x4 (&cq)[2][3], bf16x8 (&aa)[2][2], bf16x8 (&bb)[3][2]) {
    __builtin_amdgcn_s_setprio(1);
#pragma unroll
    for (int ks = 0; ks < 2; ++ks)
#pragma unroll
      for (int R = 0; R < 2; ++R)
#pragma unroll
        for (int F = 0; F < 3; ++F)
          cq[R][F] = __builtin_amdgcn_mfma_f32_16x16x32_bf16(aa[R][ks], bb[F][ks], cq[R][F], 0, 0, 0);
    __builtin_amdgcn_s_setprio(0);
  };

#define SYNC_VM(NN)                                               \
  asm volatile("s_waitcnt vmcnt(" #NN ")" ::: "memory");          \
  __builtin_amdgcn_s_barrier();                                   \
  asm volatile("s_waitcnt lgkmcnt(0)" ::: "memory");              \
  __builtin_amdgcn_sched_barrier(0);
#define BARSYNC()                                                 \
  __builtin_amdgcn_s_barrier();                                   \
  asm volatile("s_waitcnt lgkmcnt(0)" ::: "memory");              \
  __builtin_amdgcn_sched_barrier(0);

  // prologue: all 4 units of tile 0 (issue order A,B0,B1,B2 = 8 loads/thread)
  stageA(0, 0); stageB(0, 0, 0); stageB(0, 1, 0); stageB(0, 2, 0);
  asm volatile("s_waitcnt vmcnt(4)" ::: "memory");  // A(0), B0(0) landed
  __builtin_amdgcn_s_barrier();

  const int NT = K >> 6;
  for (int t = 0; t < NT; ++t) {
    const int cb = t & 1, nb = cb ^ 1;
    const bool pf = (t + 1 < NT);
    // P0: quadrant (0,0) — reads A-h0, B-h0; stage A(t+1), B0(t+1)
    readAh(a0, cb, 0);
    readBh(b0, cb, 0);
    if (pf) {
      stageA(nb, t + 1); stageB(nb, 0, t + 1);
      SYNC_VM(6)                 // retires B1(t): ready for P1 reads
    } else {
      SYNC_VM(2)                 // last tile: only B1(t),B2(t) outstanding
    }
    mfma12(acc[0][0], a0, b0);
    __builtin_amdgcn_s_barrier();
    // P1: quadrant (0,1) — reads B-h1 (A-h0 reused); stage B1(t+1)
    readBh(b1, cb, 1);
    if (pf) {
      stageB(nb, 1, t + 1);
      SYNC_VM(6)                 // retires B2(t): ready for P2 reads
    } else {
      SYNC_VM(0)
    }
    mfma12(acc[0][1], a0, b1);
    __builtin_amdgcn_s_barrier();
    // P2: quadrant (1,1) — reads A-h1 (B-h1 reused); stage B2(t+1)
    readAh(a1, cb, 1);
    if (pf) stageB(nb, 2, t + 1);
    BARSYNC()                    // P3 reads nothing: no vmcnt needed
    mfma12(acc[1][1], a1, b1);
    __builtin_amdgcn_s_barrier();
    // P3: quadrant (1,0) — register reuse only; counted wait for next P0's operands
    mfma12(acc[1][0], a1, b0);
    if (pf) { asm volatile("s_waitcnt vmcnt(4)" ::: "memory"); }  // A,B0 of t+1 landed
    __builtin_amdgcn_s_barrier();
  }
#undef SYNC_VM
#undef BARSYNC

  // epilogue: bias + fp32 store
#pragma unroll
  for (int qr = 0; qr < 2; ++qr)
#pragma unroll
    for (int qc = 0; qc < 2; ++qc)
#pragma unroll
      for (int R = 0; R < 2; ++R)
#pragma unroll
        for (int F = 0; F < 3; ++F) {
          int row0 = bm * 128 + wm * 64 + qr * 32 + R * 16 + g * 4;
          int col  = bn * 384 + wn * 96 + qc * 48 + F * 16 + r16;
          float bv = bias[col];
#pragma unroll
          for (int rr = 0; rr < 4; ++rr)
            C[(size_t)(row0 + rr) * N + col] = acc[qr][qc][R][F][rr] + bv;
        }
}

// ---------------- 128x128 GEMM (2-phase dbuf): C = A @ B^T + bias ----------------
__global__ __launch_bounds__(256) void gemm_bt_bias(
    const bf16* __restrict__ A, const bf16* __restrict__ B,
    const float* __restrict__ bias, float* __restrict__ C,
    int M, int N, int K)
{
  __shared__ __align__(16) bf16 As[2][128 * 32];
  __shared__ __align__(16) bf16 Bs[2][128 * 32];
  const int tid = threadIdx.x;
  const int lane = tid & 63;
  const int w = tid >> 6;
  const int wm = (w >> 1) * 64, wn = (w & 1) * 64;
  const int g = lane >> 4;
  const int r16 = lane & 15;
  const int bm = blockIdx.y, bn = blockIdx.x;

  f32x4 acc[4][4] = {};

  const size_t Abase = (size_t)(bm * 128) * K;
  const size_t Bbase = (size_t)(bn * 128) * K;

  auto stage = [&](int bb, int k0) {
#pragma unroll
    for (int c = 0; c < 2; ++c) {
      int e = c * 256 + tid;
      int row = e >> 2, col = (e & 3) * 8;
      gload_lds16(A + Abase + (size_t)row * K + k0 + col, (char*)&As[bb][0] + (size_t)e * 16);
      gload_lds16(B + Bbase + (size_t)row * K + k0 + col, (char*)&Bs[bb][0] + (size_t)e * 16);
    }
  };

  stage(0, 0);
  __syncthreads();

  for (int k0 = 0; k0 < K; k0 += 32) {
    const int cur = (k0 >> 5) & 1;
    if (k0 + 32 < K) stage(cur ^ 1, k0 + 32);
    bf16x8 a[4], b[4];
#pragma unroll
    for (int m = 0; m < 4; ++m)
      a[m] = *reinterpret_cast<const bf16x8*>(&As[cur][(wm + m * 16 + r16) * 32 + g * 8]);
#pragma unroll
    for (int n = 0; n < 4; ++n)
      b[n] = *reinterpret_cast<const bf16x8*>(&Bs[cur][(wn + n * 16 + r16) * 32 + g * 8]);
    __builtin_amdgcn_s_setprio(1);
#pragma unroll
    for (int m = 0; m < 4; ++m)
#pragma unroll
      for (int n = 0; n < 4; ++n)
        acc[m][n] = __builtin_amdgcn_mfma_f32_16x16x32_bf16(a[m], b[n], acc[m][n], 0, 0, 0);
    __builtin_amdgcn_s_setprio(0);
    __syncthreads();
  }

#pragma unroll
  for (int m = 0; m < 4; ++m) {
    int row0 = bm * 128 + wm + m * 16 + g * 4;
#pragma unroll
    for (int n = 0; n < 4; ++n) {
      int col = bn * 128 + wn + n * 16 + r16;
      float bv = bias[col];
#pragma unroll
      for (int rr = 0; rr < 4; ++rr)
        C[(size_t)(row0 + rr) * N + col] = acc[m][n][rr] + bv;
    }
  }
}

// -------- fused LayerNorm+RoPE (blocks 0..8191) + V transpose (blocks 8192..12287) ----
__global__ __launch_bounds__(256) void lnrope_vt_kernel(
    const float* __restrict__ qkv, const float* __restrict__ qw,
    const float* __restrict__ kw, bf16* __restrict__ qo, bf16* __restrict__ ko,
    bf16* __restrict__ vt)
{
  __shared__ bf16 tile[32][33];
  const int tid = threadIdx.x;
  if (blockIdx.x < 8192) {
    const int lane = tid & 63;
    const int wid = blockIdx.x * 4 + (tid >> 6);
    const int h = wid >> 11;
    const int t = wid & (T_DIM - 1);
    const int c0 = lane * 2;

    float inv_freq = exp2f(-13.287712379549449f * (float)c0 * (1.0f / 128.0f));
    float fr = (float)t * inv_freq;
    float sn = sinf(fr), cs = cosf(fr);
    const float scaleq = 0.08838834764831845f; // 1/sqrt(128)

#pragma unroll
    for (int which = 0; which < 2; ++which) {
      const float* base = qkv + (size_t)t * (3 * D_DIM) + which * D_DIM + h * C_DIM;
      float2 v = *reinterpret_cast<const float2*>(base + c0);
      float s = v.x + v.y;
#pragma unroll
      for (int m = 32; m; m >>= 1) s += __shfl_xor(s, m);
      float mu = s * (1.0f / 128.0f);
      float d0 = v.x - mu, d1 = v.y - mu;
      float ss = d0 * d0 + d1 * d1;
#pragma unroll
      for (int m = 32; m; m >>= 1) ss += __shfl_xor(ss, m);
      float rstd = rsqrtf(ss * (1.0f / 128.0f) + 1e-6f);
      const float* wgt = which ? kw : qw;
      float x0 = d0 * rstd * wgt[c0], x1 = d1 * rstd * wgt[c0 + 1];
      float o0 = x0 * cs - x1 * sn;
      float o1 = x1 * cs + x0 * sn;
      if (!which) { o0 *= scaleq; o1 *= scaleq; }
      bf16* out = (which ? ko : qo) + ((size_t)h * T_DIM + t) * C_DIM + c0;
      bf16x2 ob; ob[0] = (bf16)o0; ob[1] = (bf16)o1;
      *reinterpret_cast<bf16x2*>(out) = ob;
    }
  } else {
    const int vb = blockIdx.x - 8192;          // 64 x 4 x 16
    const int t0 = (vb & 63) * 32;
    const int c0 = ((vb >> 6) & 3) * 32;
    const int h = vb >> 8;
    const int tx = tid & 31, ty = tid >> 5;
#pragma unroll
    for (int i = 0; i < 4; ++i) {
      int t = t0 + ty + i * 8;
      tile[ty + i * 8][tx] =
          (bf16)qkv[(size_t)t * (3 * D_DIM) + 2 * D_DIM + h * C_DIM + c0 + tx];
    }
    __syncthreads();
#pragma unroll
    for (int i = 0; i < 4; ++i) {
      int c = c0 + ty + i * 8;
      vt[((size_t)h * C_DIM + c) * T_DIM + t0 + tx] = tile[tx][ty + i * 8];
    }
  }
}

// ---------------- Flash attention (causal), swapped-QK^T lane-local softmax ----------
__global__ __launch_bounds__(256, 4) void attn_kernel(
    const bf16* __restrict__ Q, const bf16* __restrict__ K,
    const bf16* __restrict__ VT, bf16* __restrict__ AO,
    float* __restrict__ U, float* __restrict__ ML)
{
  __shared__ __align__(16) bf16 Ks[2][32 * 128];   // 16 KB
  __shared__ __align__(16) bf16 Vs[2][128 * 32];   // 16 KB
  __shared__ __align__(16) bf16 p_lds[4][16 * 32]; //  4 KB
  const int tid = threadIdx.x;
  const int lane = tid & 63;
  const int w = tid >> 6;
  const int g = lane >> 4, r16 = lane & 15;
  const int h = blockIdx.y;
  const int b = blockIdx.x;

  int qb, kb0, kb1, sp;
  if (b < 32) { qb = 16 + (b >> 1); sp = b & 1; kb0 = sp * 32; kb1 = sp ? (2 * qb + 2) : 32; }
  else        { qb = 47 - b;        sp = -1;    kb0 = 0;       kb1 = 2 * qb + 2; }
  const int qr0 = qb * 64 + w * 16;
  const int qrow = qr0 + r16;   // this lane's q-row

  const bf16* Qh = Q + (size_t)h * T_DIM * C_DIM;
  const bf16* Kh = K + (size_t)h * T_DIM * C_DIM;
  const bf16* Vh = VT + (size_t)h * C_DIM * T_DIM;

  bf16x8 qf[4];
#pragma unroll
  for (int kk = 0; kk < 4; ++kk)
    qf[kk] = *reinterpret_cast<const bf16x8*>(
        &Qh[(size_t)qrow * C_DIM + kk * 32 + g * 8]);

  float mrow = -INFINITY, lrow = 0.f;
  f32x4 o[8] = {};

  auto stage = [&](int bb, int kb) {
    const bf16* Kt = Kh + (size_t)(kb * 32) * C_DIM;
    const bf16* Vt = Vh + kb * 32;
#pragma unroll
    for (int i = 0; i < 2; ++i) {
      int e = i * 256 + tid;
      int r = e >> 4, p = e & 15, j = p ^ (r & 7);
      gload_lds16(Kt + r * C_DIM + j * 8, (char*)&Ks[bb][0] + (size_t)e * 16);
    }
#pragma unroll
    for (int i = 0; i < 2; ++i) {
      int e = i * 256 + tid;
      int r = e >> 2, p = e & 3, j = p ^ ((r >> 1) & 3);
      gload_lds16(Vt + (size_t)r * T_DIM + j * 8, (char*)&Vs[bb][0] + (size_t)e * 16);
    }
  };

  stage(0, kb0);
  __syncthreads();
  int buf = 0;

  for (int kb = kb0; kb < kb1; ++kb) {
    if (kb + 1 < kb1) stage(buf ^ 1, kb + 1);

    f32x4 sacc[2] = {};
    __builtin_amdgcn_s_setprio(1);
#pragma unroll
    for (int n = 0; n < 2; ++n) {
      int kr = n * 16 + r16;
      const bf16* kbase = &Ks[buf][kr << 7];
#pragma unroll
      for (int kk = 0; kk < 4; ++kk) {
        bf16x8 kf = *reinterpret_cast<const bf16x8*>(
            kbase + (((kk * 4 + g) ^ (kr & 7)) << 3));
        sacc[n] = __builtin_amdgcn_mfma_f32_16x16x32_bf16(kf, qf[kk], sacc[n], 0, 0, 0);
      }
    }
    __builtin_amdgcn_s_setprio(0);
    if (kb * 32 + 31 > qr0) {
#pragma unroll
      for (int n = 0; n < 2; ++n)
#pragma unroll
        for (int rr = 0; rr < 4; ++rr)
          if (kb * 32 + n * 16 + g * 4 + rr > qrow) sacc[n][rr] = -3.0e38f;
    }
    float mx = fmaxf(fmaxf(fmaxf(sacc[0][0], sacc[0][1]), fmaxf(sacc[0][2], sacc[0][3])),
                     fmaxf(fmaxf(sacc[1][0], sacc[1][1]), fmaxf(sacc[1][2], sacc[1][3])));
    mx = fmaxf(mx, __shfl_xor(mx, 16));
    mx = fmaxf(mx, __shfl_xor(mx, 32));
    float alpha = 1.0f;
    bool need = __any(mx > mrow + 8.0f);
    if (need) {
      float mnew = fmaxf(mrow, mx);
      alpha = __expf(mrow - mnew);
      mrow = mnew;
    }
    float ps = 0.f;
#pragma unroll
    for (int n = 0; n < 2; ++n)
#pragma unroll
      for (int rr = 0; rr < 4; ++rr) {
        float p = __expf(sacc[n][rr] - mrow);
        sacc[n][rr] = p;
        ps += p;
      }
    ps += __shfl_xor(ps, 16);
    ps += __shfl_xor(ps, 32);
    lrow = lrow * alpha + ps;
    if (need) {
#pragma unroll
      for (int nc = 0; nc < 8; ++nc)
#pragma unroll
        for (int rr = 0; rr < 4; ++rr)
          o[nc][rr] *= alpha;
    }
    {
      bf16* prow = &p_lds[w][r16 << 5];
      const int ssw = (r16 >> 1) & 3;
#pragma unroll
      for (int n = 0; n < 2; ++n) {
        bf16x4 pk;
        pk[0] = (bf16)sacc[n][0]; pk[1] = (bf16)sacc[n][1];
        pk[2] = (bf16)sacc[n][2]; pk[3] = (bf16)sacc[n][3];
        int c8 = 2 * n + (g >> 1);
        *reinterpret_cast<bf16x4*>(prow + (((c8 ^ ssw) << 3) | ((g & 1) << 2))) = pk;
      }
    }
    asm volatile("s_waitcnt lgkmcnt(0)" ::: "memory");
    __builtin_amdgcn_s_setprio(1);
    bf16x8 pf = *reinterpret_cast<const bf16x8*>(
        &p_lds[w][(r16 << 5) + ((g ^ ((r16 >> 1) & 3)) << 3)]);
#pragma unroll
    for (int nc = 0; nc < 8; ++nc) {
      int vr = nc * 16 + r16;
      bf16x8 vf = *reinterpret_cast<const bf16x8*>(
          &Vs[buf][(vr << 5) + ((g ^ ((vr >> 1) & 3)) << 3)]);
      o[nc] = __builtin_amdgcn_mfma_f32_16x16x32_bf16(vf, pf, o[nc], 0, 0, 0);
    }
    __builtin_amdgcn_s_setprio(0);
    __syncthreads();
    buf ^= 1;
  }

  if (sp < 0) {
    float inv = 1.0f / lrow;
    bf16* arow = &AO[(size_t)qrow * D_DIM + h * C_DIM + (g << 2)];
#pragma unroll
    for (int nc = 0; nc < 8; ++nc) {
      bf16x4 ob;
      ob[0] = (bf16)(o[nc][0] * inv); ob[1] = (bf16)(o[nc][1] * inv);
      ob[2] = (bf16)(o[nc][2] * inv); ob[3] = (bf16)(o[nc][3] * inv);
      *reinterpret_cast<bf16x4*>(arow + nc * 16) = ob;
    }
  } else {
    const int qi = qb - 16;
    const size_t ubase = ((size_t)(h * 16 + qi) * 2 + sp) * (64 * 128);
    const size_t mlbase = (size_t)(h * 16 + qi) * 256 + sp * 128;
    const int row = w * 16 + r16;
    float* urow = &U[ubase + (size_t)row * 128 + (g << 2)];
#pragma unroll
    for (int nc = 0; nc < 8; ++nc)
      *reinterpret_cast<f32x4*>(urow + nc * 16) = o[nc];
    if (g == 0) {
      ML[mlbase + row] = mrow;
      ML[mlbase + 64 + row] = lrow;
    }
  }
}

// ---------------- combine: merge the two KV-split partials for qb>=16 ----------------
__global__ __launch_bounds__(256) void attn_combine(
    const float* __restrict__ U, const float* __restrict__ ML, bf16* __restrict__ AO)
{
  int idx = blockIdx.x * 256 + threadIdx.x;
  int c4 = (idx & 31) * 4;
  int r = idx >> 5;
  int trow = r & 63;
  int qi = (r >> 6) & 15;
  int h = r >> 10;

  size_t mlbase = (size_t)(h * 16 + qi) * 256;
  float m0 = ML[mlbase + trow],       l0 = ML[mlbase + 64 + trow];
  float m1 = ML[mlbase + 128 + trow], l1 = ML[mlbase + 192 + trow];
  float m = fmaxf(m0, m1);
  float a0 = __expf(m0 - m), a1 = __expf(m1 - m);
  float inv = 1.0f / (l0 * a0 + l1 * a1);

  size_t t0 = ((size_t)(h * 16 + qi) * 2) * (64 * 128) + (size_t)trow * 128 + c4;
  float4 u0 = *reinterpret_cast<const float4*>(U + t0);
  float4 u1 = *reinterpret_cast<const float4*>(U + t0 + 64 * 128);
  int t = 1024 + qi * 64 + trow;
  bf16x4 ob;
  ob[0] = (bf16)((u0.x * a0 + u1.x * a1) * inv);
  ob[1] = (bf16)((u0.y * a0 + u1.y * a1) * inv);
  ob[2] = (bf16)((u0.z * a0 + u1.z * a1) * inv);
  ob[3] = (bf16)((u0.w * a0 + u1.w * a1) * inv);
  *reinterpret_cast<bf16x4*>(&AO[(size_t)t * D_DIM + h * C_DIM + c4]) = ob;
}

// ---------------- launch ----------------
extern "C" void kernel_launch(void* const* d_in, const int* in_sizes, int n_in,
                              void* d_out, int out_size, void* d_ws, size_t ws_size,
                              hipStream_t stream)
{
  const float* x      = (const float*)d_in[0];
  const float* W_attn = (const float*)d_in[1];
  const float* b_attn = (const float*)d_in[2];
  const float* W_proj = (const float*)d_in[3];
  const float* b_proj = (const float*)d_in[4];
  const float* q_ln_w = (const float*)d_in[5];
  const float* k_ln_w = (const float*)d_in[6];

  char* ws = (char*)d_ws;
  bf16*  x_bf  = (bf16*)(ws + 0);           //  8 MB
  bf16*  wa_bf = (bf16*)(ws + 8388608);     // 24 MB
  bf16*  wp_bf = (bf16*)(ws + 33554432);    //  8 MB
  float* qkv   = (float*)(ws + 41943040);   // 48 MB (dead after lnrope_vt)
  bf16*  q_bf  = (bf16*)(ws + 92274688);    //  8 MB
  bf16*  k_bf  = (bf16*)(ws + 100663296);   //  8 MB
  bf16*  vt    = (bf16*)(ws + 109051904);   //  8 MB
  bf16*  ao    = (bf16*)(ws + 117440512);   //  8 MB (total 120 MB)
  float* U  = (float*)(ws + 41943040);      // 16 MB (aliases dead qkv)
  float* ML = (float*)(ws + 58720256);      // 256 KB

  cvt3<<<2048, 256, 0, stream>>>(x, W_attn, W_proj, x_bf, wa_bf, wp_bf);

  gemm384_bt_bias<<<dim3((T_DIM / 128) * (3 * D_DIM / 384)), dim3(512), 0, stream>>>(
      x_bf, wa_bf, b_attn, qkv, T_DIM, 3 * D_DIM, D_DIM);

  lnrope_vt_kernel<<<8192 + 4096, 256, 0, stream>>>(qkv, q_ln_w, k_ln_w, q_bf, k_bf, vt);

  attn_kernel<<<dim3(48, H_DIM), 256, 0, stream>>>(q_bf, k_bf, vt, ao, U, ML);
  attn_combine<<<2048, 256, 0, stream>>>(U, ML, ao);

  gemm_bt_bias<<<dim3(D_DIM / 128, T_DIM / 128), 256, 0, stream>>>(
      ao, wp_bf, b_proj, (float*)d_out, T_DIM, D_DIM, D_DIM);
}

// Round 9
// 170.314 us; speedup vs baseline: 1.1070x; 1.1070x over previous
//
#include <hip/hip_runtime.h>
#include <hip/hip_bf16.h>
#include <math.h>

#define T_DIM 2048
#define D_DIM 2048
#define H_DIM 16
#define C_DIM 128

typedef __bf16 bf16;
typedef __attribute__((ext_vector_type(8))) __bf16 bf16x8;
typedef __attribute__((ext_vector_type(4))) __bf16 bf16x4;
typedef __attribute__((ext_vector_type(2))) __bf16 bf16x2;
typedef __attribute__((ext_vector_type(4))) float f32x4;

__device__ __forceinline__ void gload_lds16(const void* g, void* l) {
  __builtin_amdgcn_global_load_lds((__attribute__((address_space(1))) void*)g,
                                   (__attribute__((address_space(3))) void*)l,
                                   16, 0, 0);
}

// ---------------- fused fp32 -> bf16 conversion of x, W_attn, W_proj ----------------
__global__ __launch_bounds__(256) void cvt3(
    const float* __restrict__ x, const float* __restrict__ wa, const float* __restrict__ wp,
    bf16* __restrict__ xo, bf16* __restrict__ wao, bf16* __restrict__ wpo)
{
  const int NX = 1048576, NA = 3145728;      // float4 counts: x, W_attn (W_proj = NX)
  int i = blockIdx.x * 256 + threadIdx.x;
  for (; i < 5242880; i += 2048 * 256) {
    const float* s; bf16* d; int off;
    if (i < NX)            { s = x;  d = xo;  off = i; }
    else if (i < NX + NA)  { s = wa; d = wao; off = i - NX; }
    else                   { s = wp; d = wpo; off = i - NX - NA; }
    float4 v = reinterpret_cast<const float4*>(s)[off];
    bf16x4 o;
    o[0] = (bf16)v.x; o[1] = (bf16)v.y; o[2] = (bf16)v.z; o[3] = (bf16)v.w;
    reinterpret_cast<bf16x4*>(d)[off] = o;
  }
}

// ============ 128x384 fat-phase GEMM: C = A(MxK) @ B(NxK)^T + bias ============
// Grid = 256 blocks (100% fill), 8 waves as 2M x 4N (per-wave 64x96). ONE phase per
// K-tile: stage t+1 (8 gloads) + read all 20 fragments + 48 MFMA + __syncthreads().
// The barrier's vmcnt(0) drain is covered by the ~1550-cyc MFMA block (unlike the
// R6/R7 386-cyc phases, whose 8 barriers/K-tile fragmented the pipeline — 31% Mfma).
// LDS 128 KB (BK=64 dbuf), chunk-XOR swizzle (measured 0 conflicts).
template <typename OutT>
__global__ __launch_bounds__(512, 2) void gemm384_bt_bias(
    const bf16* __restrict__ A, const bf16* __restrict__ B,
    const float* __restrict__ bias, OutT* __restrict__ C,
    int M, int N, int K)
{
  __shared__ __align__(16) bf16 Asl[2][128 * 64];  // 32 KB
  __shared__ __align__(16) bf16 Bsl[2][384 * 64];  // 96 KB
  const int tid = threadIdx.x;
  const int lane = tid & 63;
  const int wv = tid >> 6;          // 0..7
  const int g = lane >> 4, r16 = lane & 15;
  const int wm = wv >> 2;           // 0..1 : 64-row slice
  const int wn = wv & 3;            // 0..3 : 96-col slice

  // XCD swizzle: 256 blocks, 32 contiguous per XCD
  int bid = blockIdx.x;
  int bid2 = (bid & 7) * (gridDim.x >> 3) + (bid >> 3);
  const int ntn = N / 384;
  const int bn = bid2 % ntn, bm = bid2 / ntn;

  const size_t Abase = (size_t)(bm * 128) * K;
  const size_t Bbase = (size_t)(bn * 384) * K;

  f32x4 acc[2][2][2][3] = {};          // [qr][qc][R][F]
  bf16x8 a0[2][2], a1[2][2];           // A row-halves  [R][ks]
  bf16x8 b0[3][2], b1[3][2];           // B col-halves  [F][ks]

  auto stageA = [&](int bb, int t) {
#pragma unroll
    for (int i = 0; i < 2; ++i) {
      int c = i * 512 + tid;
      int r = c >> 3, p = c & 7, j = p ^ (r & 7);
      gload_lds16(A + Abase + (size_t)r * K + t * 64 + j * 8,
                  (char*)&Asl[bb][0] + (size_t)c * 16);
    }
  };
  auto stageB = [&](int bb, int u, int t) {   // u = 0..2 -> B rows u*128..+127
#pragma unroll
    for (int i = 0; i < 2; ++i) {
      int c = i * 512 + tid;
      int r = c >> 3, p = c & 7, j = p ^ (r & 7);
      gload_lds16(B + Bbase + (size_t)(u * 128 + r) * K + t * 64 + j * 8,
                  (char*)&Bsl[bb][0] + u * 16384 + (size_t)c * 16);
    }
  };
  auto readAh = [&](bf16x8 (&dst)[2][2], int bufi, int qr) {
#pragma unroll
    for (int R = 0; R < 2; ++R) {
      int ar = wm * 64 + qr * 32 + R * 16 + r16;
#pragma unroll
      for (int ks = 0; ks < 2; ++ks)
        dst[R][ks] = *reinterpret_cast<const bf16x8*>(
            &Asl[bufi][ar * 64 + (((ks * 4 + g) ^ (ar & 7)) << 3)]);
    }
  };
  auto readBh = [&](bf16x8 (&dst)[3][2], int bufi, int qc) {
#pragma unroll
    for (int F = 0; F < 3; ++F) {
      int br = wn * 96 + qc * 48 + F * 16 + r16;
#pragma unroll
      for (int ks = 0; ks < 2; ++ks)
        dst[F][ks] = *reinterpret_cast<const bf16x8*>(
            &Bsl[bufi][br * 64 + (((ks * 4 + g) ^ (br & 7)) << 3)]);
    }
  };
  auto mfma12 = [&](f32x4 (&cq)[2][3], bf16x8 (&aa)[2][2], bf16x8 (&bb)[3][2]) {
#pragma unroll
    for (int ks = 0; ks < 2; ++ks)
#pragma unroll
      for (int R = 0; R < 2; ++R)
#pragma unroll
        for (int F = 0; F < 3; ++F)
          cq[R][F] = __builtin_amdgcn_mfma_f32_16x16x32_bf16(aa[R][ks], bb[F][ks], cq[R][F], 0, 0, 0);
  };

  // prologue: tile 0 fully staged
  stageA(0, 0); stageB(0, 0, 0); stageB(0, 1, 0); stageB(0, 2, 0);
  __syncthreads();

  const int NT = K >> 6;
  for (int t = 0; t < NT; ++t) {
    const int cb = t & 1, nb = cb ^ 1;
    if (t + 1 < NT) {  // stage next tile; lands during this tile's MFMA block
      stageA(nb, t + 1); stageB(nb, 0, t + 1); stageB(nb, 1, t + 1); stageB(nb, 2, t + 1);
    }
    readAh(a0, cb, 0); readAh(a1, cb, 1);
    readBh(b0, cb, 0); readBh(b1, cb, 1);
    mfma12(acc[0][0], a0, b0);
    mfma12(acc[0][1], a0, b1);
    mfma12(acc[1][1], a1, b1);
    mfma12(acc[1][0], a1, b0);
    __syncthreads();   // vmcnt(0)+lgkmcnt(0)+barrier; drain covered by MFMA duration
  }

  // epilogue: bias + store
#pragma unroll
  for (int qr = 0; qr < 2; ++qr)
#pragma unroll
    for (int qc = 0; qc < 2; ++qc)
#pragma unroll
      for (int R = 0; R < 2; ++R)
#pragma unroll
        for (int F = 0; F < 3; ++F) {
          int row0 = bm * 128 + wm * 64 + qr * 32 + R * 16 + g * 4;
          int col  = bn * 384 + wn * 96 + qc * 48 + F * 16 + r16;
          float bv = bias[col];
#pragma unroll
          for (int rr = 0; rr < 4; ++rr)
            C[(size_t)(row0 + rr) * N + col] = (OutT)(acc[qr][qc][R][F][rr] + bv);
        }
}

// ---------------- 128x128 fat-phase GEMM (BK=64 dbuf, 2 blocks/CU): fp32 out --------
__global__ __launch_bounds__(256, 2) void gemm_bt_bias(
    const bf16* __restrict__ A, const bf16* __restrict__ B,
    const float* __restrict__ bias, float* __restrict__ C,
    int M, int N, int K)
{
  __shared__ __align__(16) bf16 As[2][128 * 64];  // 32 KB
  __shared__ __align__(16) bf16 Bs[2][128 * 64];  // 32 KB
  const int tid = threadIdx.x;
  const int lane = tid & 63;
  const int w = tid >> 6;
  const int wm = (w >> 1) * 64, wn = (w & 1) * 64;
  const int g = lane >> 4;
  const int r16 = lane & 15;

  // XCD swizzle over the 2D grid
  int lb = blockIdx.y * gridDim.x + blockIdx.x;
  int nblk = gridDim.x * gridDim.y;
  int s = (lb & 7) * (nblk >> 3) + (lb >> 3);
  const int bn = s % gridDim.x, bm = s / gridDim.x;

  f32x4 acc[4][4] = {};

  const size_t Abase = (size_t)(bm * 128) * K;
  const size_t Bbase = (size_t)(bn * 128) * K;

  auto stage = [&](int bb, int t) {
#pragma unroll
    for (int i = 0; i < 4; ++i) {
      int c = i * 256 + tid;                       // 0..1023 chunks per operand
      int r = c >> 3, p = c & 7, j = p ^ (r & 7);
      gload_lds16(A + Abase + (size_t)r * K + t * 64 + j * 8,
                  (char*)&As[bb][0] + (size_t)c * 16);
      gload_lds16(B + Bbase + (size_t)r * K + t * 64 + j * 8,
                  (char*)&Bs[bb][0] + (size_t)c * 16);
    }
  };

  stage(0, 0);
  __syncthreads();

  const int NT = K >> 6;
  for (int t = 0; t < NT; ++t) {
    const int cb = t & 1, nb = cb ^ 1;
    if (t + 1 < NT) stage(nb, t + 1);
    bf16x8 a[4][2], b[4][2];
#pragma unroll
    for (int m = 0; m < 4; ++m) {
      int ar = wm + m * 16 + r16;
#pragma unroll
      for (int ks = 0; ks < 2; ++ks)
        a[m][ks] = *reinterpret_cast<const bf16x8*>(
            &As[cb][ar * 64 + (((ks * 4 + g) ^ (ar & 7)) << 3)]);
    }
#pragma unroll
    for (int n = 0; n < 4; ++n) {
      int br = wn + n * 16 + r16;
#pragma unroll
      for (int ks = 0; ks < 2; ++ks)
        b[n][ks] = *reinterpret_cast<const bf16x8*>(
            &Bs[cb][br * 64 + (((ks * 4 + g) ^ (br & 7)) << 3)]);
    }
#pragma unroll
    for (int ks = 0; ks < 2; ++ks)
#pragma unroll
      for (int m = 0; m < 4; ++m)
#pragma unroll
        for (int n = 0; n < 4; ++n)
          acc[m][n] = __builtin_amdgcn_mfma_f32_16x16x32_bf16(a[m][ks], b[n][ks], acc[m][n], 0, 0, 0);
    __syncthreads();
  }

#pragma unroll
  for (int m = 0; m < 4; ++m) {
    int row0 = bm * 128 + wm + m * 16 + g * 4;
#pragma unroll
    for (int n = 0; n < 4; ++n) {
      int col = bn * 128 + wn + n * 16 + r16;
      float bv = bias[col];
#pragma unroll
      for (int rr = 0; rr < 4; ++rr)
        C[(size_t)(row0 + rr) * N + col] = acc[m][n][rr] + bv;
    }
  }
}

// -------- fused LayerNorm+RoPE (blocks 0..8191) + V transpose (blocks 8192..12287) ----
// qkv is bf16 now (half the read traffic of the fp32 version).
__global__ __launch_bounds__(256) void lnrope_vt_kernel(
    const bf16* __restrict__ qkv, const float* __restrict__ qw,
    const float* __restrict__ kw, bf16* __restrict__ qo, bf16* __restrict__ ko,
    bf16* __restrict__ vt)
{
  __shared__ bf16 tile[32][33];
  const int tid = threadIdx.x;
  if (blockIdx.x < 8192) {
    const int lane = tid & 63;
    const int wid = blockIdx.x * 4 + (tid >> 6);
    const int h = wid >> 11;
    const int t = wid & (T_DIM - 1);
    const int c0 = lane * 2;

    float inv_freq = exp2f(-13.287712379549449f * (float)c0 * (1.0f / 128.0f));
    float fr = (float)t * inv_freq;
    float sn = sinf(fr), cs = cosf(fr);
    const float scaleq = 0.08838834764831845f; // 1/sqrt(128)

#pragma unroll
    for (int which = 0; which < 2; ++which) {
      const bf16* base = qkv + (size_t)t * (3 * D_DIM) + which * D_DIM + h * C_DIM;
      bf16x2 v2 = *reinterpret_cast<const bf16x2*>(base + c0);
      float vx = (float)v2[0], vy = (float)v2[1];
      float s = vx + vy;
#pragma unroll
      for (int m = 32; m; m >>= 1) s += __shfl_xor(s, m);
      float mu = s * (1.0f / 128.0f);
      float d0 = vx - mu, d1 = vy - mu;
      float ss = d0 * d0 + d1 * d1;
#pragma unroll
      for (int m = 32; m; m >>= 1) ss += __shfl_xor(ss, m);
      float rstd = rsqrtf(ss * (1.0f / 128.0f) + 1e-6f);
      const float* wgt = which ? kw : qw;
      float x0 = d0 * rstd * wgt[c0], x1 = d1 * rstd * wgt[c0 + 1];
      float o0 = x0 * cs - x1 * sn;
      float o1 = x1 * cs + x0 * sn;
      if (!which) { o0 *= scaleq; o1 *= scaleq; }
      bf16* out = (which ? ko : qo) + ((size_t)h * T_DIM + t) * C_DIM + c0;
      bf16x2 ob; ob[0] = (bf16)o0; ob[1] = (bf16)o1;
      *reinterpret_cast<bf16x2*>(out) = ob;
    }
  } else {
    const int vb = blockIdx.x - 8192;          // 64 x 4 x 16
    const int t0 = (vb & 63) * 32;
    const int c0 = ((vb >> 6) & 3) * 32;
    const int h = vb >> 8;
    const int tx = tid & 31, ty = tid >> 5;
#pragma unroll
    for (int i = 0; i < 4; ++i) {
      int t = t0 + ty + i * 8;
      tile[ty + i * 8][tx] =
          qkv[(size_t)t * (3 * D_DIM) + 2 * D_DIM + h * C_DIM + c0 + tx];
    }
    __syncthreads();
#pragma unroll
    for (int i = 0; i < 4; ++i) {
      int c = c0 + ty + i * 8;
      vt[((size_t)h * C_DIM + c) * T_DIM + t0 + tx] = tile[tx][ty + i * 8];
    }
  }
}

// ---------------- Flash attention (causal), swapped-QK^T lane-local softmax ----------
__global__ __launch_bounds__(256, 4) void attn_kernel(
    const bf16* __restrict__ Q, const bf16* __restrict__ K,
    const bf16* __restrict__ VT, bf16* __restrict__ AO,
    float* __restrict__ U, float* __restrict__ ML)
{
  __shared__ __align__(16) bf16 Ks[2][32 * 128];   // 16 KB
  __shared__ __align__(16) bf16 Vs[2][128 * 32];   // 16 KB
  __shared__ __align__(16) bf16 p_lds[4][16 * 32]; //  4 KB
  const int tid = threadIdx.x;
  const int lane = tid & 63;
  const int w = tid >> 6;
  const int g = lane >> 4, r16 = lane & 15;
  const int h = blockIdx.y;
  const int b = blockIdx.x;

  int qb, kb0, kb1, sp;
  if (b < 32) { qb = 16 + (b >> 1); sp = b & 1; kb0 = sp * 32; kb1 = sp ? (2 * qb + 2) : 32; }
  else        { qb = 47 - b;        sp = -1;    kb0 = 0;       kb1 = 2 * qb + 2; }
  const int qr0 = qb * 64 + w * 16;
  const int qrow = qr0 + r16;   // this lane's q-row

  const bf16* Qh = Q + (size_t)h * T_DIM * C_DIM;
  const bf16* Kh = K + (size_t)h * T_DIM * C_DIM;
  const bf16* Vh = VT + (size_t)h * C_DIM * T_DIM;

  bf16x8 qf[4];
#pragma unroll
  for (int kk = 0; kk < 4; ++kk)
    qf[kk] = *reinterpret_cast<const bf16x8*>(
        &Qh[(size_t)qrow * C_DIM + kk * 32 + g * 8]);

  float mrow = -INFINITY, lrow = 0.f;
  f32x4 o[8] = {};

  auto stage = [&](int bb, int kb) {
    const bf16* Kt = Kh + (size_t)(kb * 32) * C_DIM;
    const bf16* Vt = Vh + kb * 32;
#pragma unroll
    for (int i = 0; i < 2; ++i) {
      int e = i * 256 + tid;
      int r = e >> 4, p = e & 15, j = p ^ (r & 7);
      gload_lds16(Kt + r * C_DIM + j * 8, (char*)&Ks[bb][0] + (size_t)e * 16);
    }
#pragma unroll
    for (int i = 0; i < 2; ++i) {
      int e = i * 256 + tid;
      int r = e >> 2, p = e & 3, j = p ^ ((r >> 1) & 3);
      gload_lds16(Vt + (size_t)r * T_DIM + j * 8, (char*)&Vs[bb][0] + (size_t)e * 16);
    }
  };

  stage(0, kb0);
  __syncthreads();
  int buf = 0;

  for (int kb = kb0; kb < kb1; ++kb) {
    if (kb + 1 < kb1) stage(buf ^ 1, kb + 1);

    f32x4 sacc[2] = {};
    __builtin_amdgcn_s_setprio(1);
#pragma unroll
    for (int n = 0; n < 2; ++n) {
      int kr = n * 16 + r16;
      const bf16* kbase = &Ks[buf][kr << 7];
#pragma unroll
      for (int kk = 0; kk < 4; ++kk) {
        bf16x8 kf = *reinterpret_cast<const bf16x8*>(
            kbase + (((kk * 4 + g) ^ (kr & 7)) << 3));
        sacc[n] = __builtin_amdgcn_mfma_f32_16x16x32_bf16(kf, qf[kk], sacc[n], 0, 0, 0);
      }
    }
    __builtin_amdgcn_s_setprio(0);
    if (kb * 32 + 31 > qr0) {
#pragma unroll
      for (int n = 0; n < 2; ++n)
#pragma unroll
        for (int rr = 0; rr < 4; ++rr)
          if (kb * 32 + n * 16 + g * 4 + rr > qrow) sacc[n][rr] = -3.0e38f;
    }
    float mx = fmaxf(fmaxf(fmaxf(sacc[0][0], sacc[0][1]), fmaxf(sacc[0][2], sacc[0][3])),
                     fmaxf(fmaxf(sacc[1][0], sacc[1][1]), fmaxf(sacc[1][2], sacc[1][3])));
    mx = fmaxf(mx, __shfl_xor(mx, 16));
    mx = fmaxf(mx, __shfl_xor(mx, 32));
    float alpha = 1.0f;
    bool need = __any(mx > mrow + 8.0f);
    if (need) {
      float mnew = fmaxf(mrow, mx);
      alpha = __expf(mrow - mnew);
      mrow = mnew;
    }
    float ps = 0.f;
#pragma unroll
    for (int n = 0; n < 2; ++n)
#pragma unroll
      for (int rr = 0; rr < 4; ++rr) {
        float p = __expf(sacc[n][rr] - mrow);
        sacc[n][rr] = p;
        ps += p;
      }
    ps += __shfl_xor(ps, 16);
    ps += __shfl_xor(ps, 32);
    lrow = lrow * alpha + ps;
    if (need) {
#pragma unroll
      for (int nc = 0; nc < 8; ++nc)
#pragma unroll
        for (int rr = 0; rr < 4; ++rr)
          o[nc][rr] *= alpha;
    }
    {
      bf16* prow = &p_lds[w][r16 << 5];
      const int ssw = (r16 >> 1) & 3;
#pragma unroll
      for (int n = 0; n < 2; ++n) {
        bf16x4 pk;
        pk[0] = (bf16)sacc[n][0]; pk[1] = (bf16)sacc[n][1];
        pk[2] = (bf16)sacc[n][2]; pk[3] = (bf16)sacc[n][3];
        int c8 = 2 * n + (g >> 1);
        *reinterpret_cast<bf16x4*>(prow + (((c8 ^ ssw) << 3) | ((g & 1) << 2))) = pk;
      }
    }
    asm volatile("s_waitcnt lgkmcnt(0)" ::: "memory");
    __builtin_amdgcn_s_setprio(1);
    bf16x8 pf = *reinterpret_cast<const bf16x8*>(
        &p_lds[w][(r16 << 5) + ((g ^ ((r16 >> 1) & 3)) << 3)]);
#pragma unroll
    for (int nc = 0; nc < 8; ++nc) {
      int vr = nc * 16 + r16;
      bf16x8 vf = *reinterpret_cast<const bf16x8*>(
          &Vs[buf][(vr << 5) + ((g ^ ((vr >> 1) & 3)) << 3)]);
      o[nc] = __builtin_amdgcn_mfma_f32_16x16x32_bf16(vf, pf, o[nc], 0, 0, 0);
    }
    __builtin_amdgcn_s_setprio(0);
    __syncthreads();
    buf ^= 1;
  }

  if (sp < 0) {
    float inv = 1.0f / lrow;
    bf16* arow = &AO[(size_t)qrow * D_DIM + h * C_DIM + (g << 2)];
#pragma unroll
    for (int nc = 0; nc < 8; ++nc) {
      bf16x4 ob;
      ob[0] = (bf16)(o[nc][0] * inv); ob[1] = (bf16)(o[nc][1] * inv);
      ob[2] = (bf16)(o[nc][2] * inv); ob[3] = (bf16)(o[nc][3] * inv);
      *reinterpret_cast<bf16x4*>(arow + nc * 16) = ob;
    }
  } else {
    const int qi = qb - 16;
    const size_t ubase = ((size_t)(h * 16 + qi) * 2 + sp) * (64 * 128);
    const size_t mlbase = (size_t)(h * 16 + qi) * 256 + sp * 128;
    const int row = w * 16 + r16;
    float* urow = &U[ubase + (size_t)row * 128 + (g << 2)];
#pragma unroll
    for (int nc = 0; nc < 8; ++nc)
      *reinterpret_cast<f32x4*>(urow + nc * 16) = o[nc];
    if (g == 0) {
      ML[mlbase + row] = mrow;
      ML[mlbase + 64 + row] = lrow;
    }
  }
}

// ---------------- combine: merge the two KV-split partials for qb>=16 ----------------
__global__ __launch_bounds__(256) void attn_combine(
    const float* __restrict__ U, const float* __restrict__ ML, bf16* __restrict__ AO)
{
  int idx = blockIdx.x * 256 + threadIdx.x;
  int c4 = (idx & 31) * 4;
  int r = idx >> 5;
  int trow = r & 63;
  int qi = (r >> 6) & 15;
  int h = r >> 10;

  size_t mlbase = (size_t)(h * 16 + qi) * 256;
  float m0 = ML[mlbase + trow],       l0 = ML[mlbase + 64 + trow];
  float m1 = ML[mlbase + 128 + trow], l1 = ML[mlbase + 192 + trow];
  float m = fmaxf(m0, m1);
  float a0 = __expf(m0 - m), a1 = __expf(m1 - m);
  float inv = 1.0f / (l0 * a0 + l1 * a1);

  size_t t0 = ((size_t)(h * 16 + qi) * 2) * (64 * 128) + (size_t)trow * 128 + c4;
  float4 u0 = *reinterpret_cast<const float4*>(U + t0);
  float4 u1 = *reinterpret_cast<const float4*>(U + t0 + 64 * 128);
  int t = 1024 + qi * 64 + trow;
  bf16x4 ob;
  ob[0] = (bf16)((u0.x * a0 + u1.x * a1) * inv);
  ob[1] = (bf16)((u0.y * a0 + u1.y * a1) * inv);
  ob[2] = (bf16)((u0.z * a0 + u1.z * a1) * inv);
  ob[3] = (bf16)((u0.w * a0 + u1.w * a1) * inv);
  *reinterpret_cast<bf16x4*>(&AO[(size_t)t * D_DIM + h * C_DIM + c4]) = ob;
}

// ---------------- launch ----------------
extern "C" void kernel_launch(void* const* d_in, const int* in_sizes, int n_in,
                              void* d_out, int out_size, void* d_ws, size_t ws_size,
                              hipStream_t stream)
{
  const float* x      = (const float*)d_in[0];
  const float* W_attn = (const float*)d_in[1];
  const float* b_attn = (const float*)d_in[2];
  const float* W_proj = (const float*)d_in[3];
  const float* b_proj = (const float*)d_in[4];
  const float* q_ln_w = (const float*)d_in[5];
  const float* k_ln_w = (const float*)d_in[6];

  char* ws = (char*)d_ws;
  bf16*  x_bf  = (bf16*)(ws + 0);           //  8 MB
  bf16*  wa_bf = (bf16*)(ws + 8388608);     // 24 MB
  bf16*  wp_bf = (bf16*)(ws + 33554432);    //  8 MB
  bf16*  qkv   = (bf16*)(ws + 41943040);    // 24 MB (bf16 now; dead after lnrope_vt)
  float* U     = (float*)(ws + 67108864);   // 16 MB
  float* ML    = (float*)(ws + 83886080);   // 256 KB
  bf16*  q_bf  = (bf16*)(ws + 92274688);    //  8 MB
  bf16*  k_bf  = (bf16*)(ws + 100663296);   //  8 MB
  bf16*  vt    = (bf16*)(ws + 109051904);   //  8 MB
  bf16*  ao    = (bf16*)(ws + 117440512);   //  8 MB (total 120 MB)

  cvt3<<<2048, 256, 0, stream>>>(x, W_attn, W_proj, x_bf, wa_bf, wp_bf);

  gemm384_bt_bias<bf16><<<dim3((T_DIM / 128) * (3 * D_DIM / 384)), dim3(512), 0, stream>>>(
      x_bf, wa_bf, b_attn, qkv, T_DIM, 3 * D_DIM, D_DIM);

  lnrope_vt_kernel<<<8192 + 4096, 256, 0, stream>>>(qkv, q_ln_w, k_ln_w, q_bf, k_bf, vt);

  attn_kernel<<<dim3(48, H_DIM), 256, 0, stream>>>(q_bf, k_bf, vt, ao, U, ML);
  attn_combine<<<2048, 256, 0, stream>>>(U, ML, ao);

  gemm_bt_bias<<<dim3(D_DIM / 128, T_DIM / 128), 256, 0, stream>>>(
      ao, wp_bf, b_proj, (float*)d_out, T_DIM, D_DIM, D_DIM);
}